// Round 1
// baseline (964.547 us; speedup 1.0000x reference)
//
#include <hip/hip_runtime.h>
#include <cstdint>
#include <cstddef>

// Problem dims: B=4, H=192, W=640, C=64, sr=2
// Conv chans: 69 -> 128 -> 128 -> 96 -> 64 -> 32 -> 1, 3x3 SAME, NHWC/HWIO.
//
// Round 4 -> 5: round-4 K-loop was L1-port-bound: 4 B-loads per 4 MFMAs =
// 1024 B/MFMA = 127 B/cyc demand vs ~64 B/cyc L1 -> MfmaUtil capped ~25%.
// Now waves split 2-way m x 2-way n (wave = 64px x 2 n-tiles): per kb
// 2 A-loads + 2 B-loads + 4 MFMAs -> B 512 B/MFMA (63 B/cyc, fits L1),
// A 512 B/MFMA (63 B/cyc, fits 128 B/cyc LDS). acc stays 64 AGPRs.
//
// Round 5 -> 6: XCD-aware bijective block swizzle (m204 formula) on
// conv_mfma and conv_last. Each XCD gets a contiguous chunk of rows
// (x-fastest within the chunk) so the 3x dy-halo row re-reads hit that
// XCD's own L2 instead of round-tripping to HBM. Predicted: conv FETCH_SIZE
// ~2x down, dur -8..11%. Pure index remap -> correctness-neutral.

#define LEAKY_SLOPE 0.2f

typedef float  f32x16 __attribute__((ext_vector_type(16)));
typedef short  s16x8  __attribute__((ext_vector_type(8)));
typedef short  s16x4  __attribute__((ext_vector_type(4)));

__device__ __forceinline__ unsigned short f2bf(float f) {
    unsigned u = __float_as_uint(f);
    u += 0x7FFFu + ((u >> 16) & 1u);          // round-to-nearest-even
    return (unsigned short)(u >> 16);
}
__device__ __forceinline__ float bf2f(unsigned short s) {
    return __uint_as_float(((unsigned)s) << 16);
}
__device__ __forceinline__ float leaky(float v){ return v >= 0.f ? v : LEAKY_SLOPE * v; }

// Bijective XCD swizzle: dispatch round-robins flat block id over 8 XCDs
// (xcd = f & 7). Remap so XCD k processes a CONTIGUOUS chunk of work ids.
// Bijective for any T (m204): chunk sizes q+1 for xcd<r else q.
__device__ __forceinline__ int xcd_swizzle(int f, int T) {
    const int q = T >> 3, r = T & 7;
    const int xcd = f & 7, i = f >> 3;
    return (xcd < r ? xcd * (q + 1) : r * (q + 1) + (xcd - r) * q) + i;
}

// ---------------------------------------------------------------------------
// Pack HWIO fp32 weights into bf16 B-fragment order for mfma_32x32x16_bf16:
// flat = (((dydx*KB + kb)*NT + nt)*64 + lane)*8 + j
// value = w[dydx][ci = kb*16 + (lane>>5)*8 + j][co = nt*32 + (lane&31)]
// ---------------------------------------------------------------------------
__global__ __launch_bounds__(256) void pack_weights(
    const float* __restrict__ src, short* __restrict__ dst,
    int CIN, int COUT, int KB, int NT, int total)
{
    int i = blockIdx.x * 256 + threadIdx.x;
    if (i >= total) return;
    int j    = i & 7;
    int lane = (i >> 3) & 63;
    int r    = i >> 9;
    int nt = r % NT; r /= NT;
    int kb = r % KB;
    int dydx = r / KB;
    int ci = kb * 16 + ((lane >> 5) << 3) + j;
    int co = nt * 32 + (lane & 31);
    float v = (ci < CIN) ? src[((size_t)dydx * CIN + ci) * COUT + co] : 0.f;
    dst[i] = (short)f2bf(v);
}

// ---------------------------------------------------------------------------
// Fused upsample + warp + cost-volume. Block = 64 px of one row.
// Output: bf16 [px][96]: ch0..63 = left, 64..68 = cost dots, 69..95 = 0.
// LDS strides are 72 shorts (144 B) for 16-B-aligned s16x8 access.
// ---------------------------------------------------------------------------
__global__ __launch_bounds__(256) void warp_costs_kernel(
    const float* __restrict__ left, const float* __restrict__ right,
    const float* __restrict__ prev, short* __restrict__ out,
    int H, int W)
{
    __shared__ float wt0s[68], wt1s[68];
    __shared__ int   i0s[68],  i1s[68];
    __shared__ __align__(16) short warp_s[68 * 72];  // [px -2..65][64ch]
    __shared__ __align__(16) short left_s[64 * 72];

    const int tid = threadIdx.x;
    const int w0 = blockIdx.x * 64;
    const int hh = blockIdx.y % H;
    const int bb = blockIdx.y / H;
    const int H2 = H >> 1, W2 = W >> 1;

    if (tid < 68) {
        int w = w0 - 2 + tid;
        float sy = 0.5f * (float)hh - 0.25f;
        float sx = 0.5f * (float)w  - 0.25f;
        float y0f = floorf(sy), x0f = floorf(sx);
        float fy = sy - y0f, fx = sx - x0f;
        int y0 = (int)y0f, x0 = (int)x0f;
        int y0c = min(max(y0, 0), H2 - 1), y1c = min(max(y0 + 1, 0), H2 - 1);
        int x0c = min(max(x0, 0), W2 - 1), x1c = min(max(x0 + 1, 0), W2 - 1);
        const float* pb = prev + (size_t)bb * H2 * W2;
        float p00 = pb[y0c * W2 + x0c], p01 = pb[y0c * W2 + x1c];
        float p10 = pb[y1c * W2 + x0c], p11 = pb[y1c * W2 + x1c];
        float disp = (1.f - fy) * ((1.f - fx) * p00 + fx * p01)
                   + fy * ((1.f - fx) * p10 + fx * p11);
        float cx = (float)w + disp;
        float xf0 = floorf(cx), xf1 = xf0 + 1.f;
        float xmax = (float)(W - 1);
        float x0s = fminf(fmaxf(xf0, 0.f), xmax);
        float x1s = fminf(fmaxf(xf1, 0.f), xmax);
        wt0s[tid] = (xf1 - cx) * (xf0 == x0s ? 1.f : 0.f);
        wt1s[tid] = (cx - xf0) * (xf1 == x1s ? 1.f : 0.f);
        i0s[tid] = (int)x0s;
        i1s[tid] = (int)x1s;
    }
    __syncthreads();

    const float* rrow = right + (size_t)(bb * H + hh) * W * 64;
    const float* lrow = left  + (size_t)(bb * H + hh) * W * 64;
    const size_t obase = ((size_t)(bb * H + hh) * W + w0) * 96;

    for (int u = tid; u < 68 * 16; u += 256) {
        int px = u >> 4, c4 = (u & 15) * 4;
        float a = wt0s[px], b = wt1s[px];
        const float4 r0 = *(const float4*)(rrow + (size_t)i0s[px] * 64 + c4);
        const float4 r1 = *(const float4*)(rrow + (size_t)i1s[px] * 64 + c4);
        s16x4 o;
        o[0] = (short)f2bf(a * r0.x + b * r1.x);
        o[1] = (short)f2bf(a * r0.y + b * r1.y);
        o[2] = (short)f2bf(a * r0.z + b * r1.z);
        o[3] = (short)f2bf(a * r0.w + b * r1.w);
        *(s16x4*)(warp_s + px * 72 + c4) = o;
    }
    for (int u = tid; u < 64 * 16; u += 256) {
        int px = u >> 4, c4 = (u & 15) * 4;
        const float4 l = *(const float4*)(lrow + ((size_t)(w0 + px)) * 64 + c4);
        s16x4 o;
        o[0] = (short)f2bf(l.x);
        o[1] = (short)f2bf(l.y);
        o[2] = (short)f2bf(l.z);
        o[3] = (short)f2bf(l.w);
        *(s16x4*)(left_s + px * 72 + c4) = o;
        *(s16x4*)(out + obase + (size_t)px * 96 + c4) = o;
    }
    // zero pad ch 69..95
    for (int u = tid; u < 64 * 3; u += 256) {
        int px = u / 3, c = 72 + (u % 3) * 8;
        s16x8 z = {0,0,0,0,0,0,0,0};
        *(s16x8*)(out + obase + (size_t)px * 96 + c) = z;
    }
    if (tid < 64) {
        out[obase + (size_t)tid * 96 + 69] = 0;
        out[obase + (size_t)tid * 96 + 70] = 0;
        out[obase + (size_t)tid * 96 + 71] = 0;
    }
    __syncthreads();

    // cost dots: 320 (px,d) tasks, vectorized s16x8 inner loop
    for (int u = tid; u < 64 * 5; u += 256) {
        int px = u / 5, d = u - px * 5;
        int x = w0 + px + d - 2;
        float s = 0.f;
        if (x >= 0 && x < W) {
            const short* lp = left_s + px * 72;
            const short* wq = warp_s + (px + d) * 72;
#pragma unroll
            for (int c8 = 0; c8 < 8; ++c8) {
                s16x8 l8 = *(const s16x8*)(lp + c8 * 8);
                s16x8 w8 = *(const s16x8*)(wq + c8 * 8);
#pragma unroll
                for (int k = 0; k < 8; ++k)
                    s += bf2f((unsigned short)l8[k]) * bf2f((unsigned short)w8[k]);
            }
        }
        out[obase + (size_t)px * 96 + 64 + d] = (short)f2bf(s * (1.f / 64.f));
    }
}

// ---------------------------------------------------------------------------
// bf16 MFMA 3x3 conv (implicit GEMM, mfma_f32_32x32x16_bf16).
// Block covers 128 px of one row x all COUT. TPB = 256 (4 waves) or 128 (2).
// Wave (wm, wn): wm owns 64 px (MT=2 m-tiles), wn owns NTW n-tiles.
//   NT=4: WN=2, NTW=2 | NT=3: WN=2, NTW=2 (tile 3 skipped) | NT=2: WN=2,
//   NTW=1 | NT=1: TPB=128, WN=1, NTW=1.
// Per kb: MT A ds_read_b128 + NTW B global loads + MT*NTW MFMAs
//   -> A and B both ~512 B/MFMA (fits LDS 128 B/cyc and L1 ~64 B/cyc ports).
// A staged per-dy in LDS, XOR-swizzled at 8-ch granularity.
// Blocks XCD-swizzled: contiguous row-chunks per XCD so dy-halo re-reads
// are L2-hits (reuse distance ~2 rows ~3.4 MB < 4 MiB per-XCD L2).
// ---------------------------------------------------------------------------
template <int CINP, int COUT, int TPB, bool RELU>
__global__ __launch_bounds__(TPB, 3) void conv_mfma(
    const short* __restrict__ in, const short* __restrict__ wp,
    const float* __restrict__ bias, short* __restrict__ out,
    int H, int W)
{
    constexpr int KB   = CINP / 16;                  // K-steps per (dy,dx)
    constexpr int NT   = COUT / 32;                  // n-tiles total
    constexpr int CIN8 = CINP / 8;
    constexpr int SL8  = (CINP == 96) ? 16 : CIN8;   // LDS ch8-slots/px (pow2)
    constexpr int WN   = (NT >= 2) ? 2 : 1;          // n-split ways
    constexpr int WM   = (TPB / 64) / WN;            // m-split ways
    constexpr int MT   = 4 / WM;                     // m-tiles per wave
    constexpr int NTW  = (NT + WN - 1) / WN;         // n-tiles per wave
    __shared__ __align__(16) short lds[132 * SL8 * 8];

    const int tid  = threadIdx.x;
    const int lane = tid & 63;
    const int wave = tid >> 6;
    const int wn   = wave % WN;
    const int wm   = wave / WN;
    const int l31  = lane & 31;
    const int lhi  = lane >> 5;

    // XCD-aware remap (bijective): contiguous rows per XCD, x fastest.
    const int nbx  = gridDim.x;
    const int work = xcd_swizzle(blockIdx.y * nbx + blockIdx.x,
                                 nbx * gridDim.y);
    const int w0 = (work % nbx) * 128;
    const int by = work / nbx;
    const int hh = by % H;
    const int bb = by / H;

    f32x16 acc[MT][NTW];
#pragma unroll
    for (int mt = 0; mt < MT; ++mt)
#pragma unroll
        for (int j = 0; j < NTW; ++j)
#pragma unroll
            for (int r = 0; r < 16; ++r) acc[mt][j][r] = 0.f;

    for (int dy = 0; dy < 3; ++dy) {
        __syncthreads();
        const int h = hh + dy - 1;
        const bool rowok = (h >= 0) && (h < H);
        const short* src = in + (size_t)(bb * H + h) * W * CINP;
        for (int u = tid; u < 130 * CIN8; u += TPB) {
            int px = u / CIN8;
            int c8 = u - px * CIN8;
            int x = w0 - 1 + px;
            s16x8 v = {0,0,0,0,0,0,0,0};
            if (rowok && x >= 0 && x < W)
                v = *(const s16x8*)(src + (size_t)x * CINP + c8 * 8);
            *(s16x8*)(&lds[(px * SL8 + (c8 ^ (px & 7))) * 8]) = v;
        }
        __syncthreads();

#pragma unroll
        for (int dx = 0; dx < 3; ++dx) {
            const short* wdx = wp + (size_t)((dy * 3 + dx) * KB) * NT * 512;
#pragma unroll 2
            for (int kb = 0; kb < KB; ++kb) {
                const int c8r = kb * 2 + lhi;
                s16x8 a[MT];
#pragma unroll
                for (int mt = 0; mt < MT; ++mt) {
                    const int px = (wm * MT + mt) * 32 + l31 + dx;
                    a[mt] = *(const s16x8*)(&lds[(px * SL8 + (c8r ^ (px & 7))) * 8]);
                }
                s16x8 b[NTW];
#pragma unroll
                for (int j = 0; j < NTW; ++j) {
                    const int tile = wn * NTW + j;
                    if (tile < NT)
                        b[j] = *(const s16x8*)(wdx + ((size_t)(kb * NT + tile) * 64 + lane) * 8);
                }
#pragma unroll
                for (int j = 0; j < NTW; ++j) {
                    if (wn * NTW + j >= NT) continue;
#pragma unroll
                    for (int mt = 0; mt < MT; ++mt)
                        acc[mt][j] = __builtin_amdgcn_mfma_f32_32x32x16_bf16(
                            a[mt], b[j], acc[mt][j], 0, 0, 0);
                }
            }
        }
    }

    // epilogue: C/D layout col(co)=lane&31, row(px)=(r&3)+8*(r>>2)+4*(lane>>5)
    const size_t rowbase = (size_t)(bb * H + hh) * W + w0;
#pragma unroll
    for (int j = 0; j < NTW; ++j) {
        const int tile = wn * NTW + j;
        if (tile >= NT) continue;
        const int co = tile * 32 + l31;
        const float bv = bias[co];
#pragma unroll
        for (int mt = 0; mt < MT; ++mt) {
            const int pxb = (wm * MT + mt) * 32 + 4 * lhi;
#pragma unroll
            for (int r = 0; r < 16; ++r) {
                int px = pxb + (r & 3) + 8 * (r >> 2);
                float v = acc[mt][j][r] + bv;
                if (RELU) v = leaky(v);
                out[(rowbase + px) * COUT + co] = (short)f2bf(v);
            }
        }
    }
}

// ---------------------------------------------------------------------------
// Final conv 32 -> 1, linear, bf16 in / fp32 out. One thread per pixel.
// XCD-swizzled block index: contiguous px-chunks (rows) per XCD so the
// 3x dy re-reads of each 32-ch row hit that XCD's L2.
// ---------------------------------------------------------------------------
__global__ __launch_bounds__(256) void conv_last_kernel(
    const short* __restrict__ in, const float* __restrict__ wgt,
    const float* __restrict__ bias, float* __restrict__ out,
    int H, int W, int npx)
{
    int blk = xcd_swizzle(blockIdx.x, gridDim.x);
    int idx = blk * 256 + threadIdx.x;
    if (idx >= npx) return;
    int w = idx % W;
    int t = idx / W;
    int h = t % H;
    int b = t / H;

    float acc = bias[0];
#pragma unroll
    for (int dy = 0; dy < 3; ++dy) {
        int hy = h + dy - 1;
        if (hy < 0 || hy >= H) continue;
#pragma unroll
        for (int dx = 0; dx < 3; ++dx) {
            int x = w + dx - 1;
            if (x < 0 || x >= W) continue;
            const short* p = in + ((size_t)(b * H + hy) * W + x) * 32;
            const float* wk = wgt + (dy * 3 + dx) * 32;
#pragma unroll
            for (int c8 = 0; c8 < 4; ++c8) {
                s16x8 v = *(const s16x8*)(p + c8 * 8);
#pragma unroll
                for (int k = 0; k < 8; ++k)
                    acc += bf2f((unsigned short)v[k]) * wk[c8 * 8 + k];
            }
        }
    }
    out[idx] = acc;
}

// ---------------------------------------------------------------------------
extern "C" void kernel_launch(void* const* d_in, const int* in_sizes, int n_in,
                              void* d_out, int out_size, void* d_ws, size_t ws_size,
                              hipStream_t stream)
{
    constexpr int B = 4, H = 192, W = 640;
    constexpr int HW = H * W;          // 122880

    const float* left  = (const float*)d_in[0];
    const float* right = (const float*)d_in[1];
    const float* prev  = (const float*)d_in[2];
    const float* w1 = (const float*)d_in[4];
    const float* b1 = (const float*)d_in[5];
    const float* w2 = (const float*)d_in[6];
    const float* b2 = (const float*)d_in[7];
    const float* w3 = (const float*)d_in[8];
    const float* b3 = (const float*)d_in[9];
    const float* w4 = (const float*)d_in[10];
    const float* b4 = (const float*)d_in[11];
    const float* w5 = (const float*)d_in[12];
    const float* b5 = (const float*)d_in[13];
    const float* w6 = (const float*)d_in[14];
    const float* b6 = (const float*)d_in[15];
    float* out = (float*)d_out;

    // Packed-weight region (shorts), then bf16 activation ping-pong X/Y.
    constexpr int S1 = 9 * 6 * 4 * 512;   // conv1: CINP 96,  COUT 128
    constexpr int S2 = 9 * 8 * 4 * 512;   // conv2: 128 -> 128
    constexpr int S3 = 9 * 8 * 3 * 512;   // conv3: 128 -> 96
    constexpr int S4 = 9 * 6 * 2 * 512;   // conv4: 96  -> 64
    constexpr int S5 = 9 * 4 * 1 * 512;   // conv5: 64  -> 32
    constexpr int P1 = 0, P2 = P1 + S1, P3 = P2 + S2, P4 = P3 + S3, P5 = P4 + S4;
    constexpr size_t WPAD = 524288;       // 1 MiB reserved (in shorts)

    short* wsS = (short*)d_ws;
    pack_weights<<<(S1 + 255) / 256, 256, 0, stream>>>(w1, wsS + P1,  69, 128, 6, 4, S1);
    pack_weights<<<(S2 + 255) / 256, 256, 0, stream>>>(w2, wsS + P2, 128, 128, 8, 4, S2);
    pack_weights<<<(S3 + 255) / 256, 256, 0, stream>>>(w3, wsS + P3, 128,  96, 8, 3, S3);
    pack_weights<<<(S4 + 255) / 256, 256, 0, stream>>>(w4, wsS + P4,  96,  64, 6, 2, S4);
    pack_weights<<<(S5 + 255) / 256, 256, 0, stream>>>(w5, wsS + P5,  64,  32, 4, 1, S5);

    // batch tiling from ws_size (deterministic -> graph-capture safe)
    auto need = [&](int nb) -> size_t {
        return (WPAD + 2ull * nb * HW * 128) * sizeof(short);
    };
    int nb = 1;
    if (ws_size >= need(4)) nb = 4;
    else if (ws_size >= need(2)) nb = 2;

    const int H2 = H / 2, W2 = W / 2;

    for (int b0 = 0; b0 < B; b0 += nb) {
        const int npx = nb * HW;
        short* X = wsS + WPAD;
        short* Y = X + (size_t)nb * HW * 128;

        const float* leftb  = left  + (size_t)b0 * HW * 64;
        const float* rightb = right + (size_t)b0 * HW * 64;
        const float* prevb  = prev  + (size_t)b0 * H2 * W2;
        float* outb = out + (size_t)b0 * HW;

        warp_costs_kernel<<<dim3(W / 64, nb * H), 256, 0, stream>>>(
            leftb, rightb, prevb, X, H, W);

        conv_mfma< 96, 128, 256, true><<<dim3(W / 128, nb * H), 256, 0, stream>>>(
            X, wsS + P1, b1, Y, H, W);
        conv_mfma<128, 128, 256, true><<<dim3(W / 128, nb * H), 256, 0, stream>>>(
            Y, wsS + P2, b2, X, H, W);
        conv_mfma<128,  96, 256, true><<<dim3(W / 128, nb * H), 256, 0, stream>>>(
            X, wsS + P3, b3, Y, H, W);
        conv_mfma< 96,  64, 256, true><<<dim3(W / 128, nb * H), 256, 0, stream>>>(
            Y, wsS + P4, b4, X, H, W);
        conv_mfma< 64,  32, 128, true><<<dim3(W / 128, nb * H), 128, 0, stream>>>(
            X, wsS + P5, b5, Y, H, W);

        conv_last_kernel<<<(npx + 255) / 256, 256, 0, stream>>>(
            Y, w6, b6, outb, H, W, npx);
    }
}

// Round 2
// 960.514 us; speedup vs baseline: 1.0042x; 1.0042x over previous
//
#include <hip/hip_runtime.h>
#include <cstdint>
#include <cstddef>

// Problem dims: B=4, H=192, W=640, C=64, sr=2
// Conv chans: 69 -> 128 -> 128 -> 96 -> 64 -> 32 -> 1, 3x3 SAME, NHWC/HWIO.
//
// Round 5 -> 6: XCD-aware bijective block swizzle (m204) on conv_mfma /
// conv_last. 1008.6 -> 964.5 us; counters showed convs are NOT HBM-bound
// (12% peak) -- MfmaUtil 24%, latency-bound on B-weight global loads.
//
// Round 6 -> 7: B-fragment double-buffered register pipeline. Per dy,
// 6 steps (3 dx x 2 half-K). Step s+1's B loads (HK x NTW x 16B) issue
// during step s's MFMAs; step 0's loads issue before the staging barrier
// (latency hides under the barrier drain). B regs 2 x HK x NTW x 4 = 64
// VGPR worst case -> still 3 waves/SIMD. Predicted MfmaUtil 24 -> ~35%.

#define LEAKY_SLOPE 0.2f

typedef float  f32x16 __attribute__((ext_vector_type(16)));
typedef short  s16x8  __attribute__((ext_vector_type(8)));
typedef short  s16x4  __attribute__((ext_vector_type(4)));

__device__ __forceinline__ unsigned short f2bf(float f) {
    unsigned u = __float_as_uint(f);
    u += 0x7FFFu + ((u >> 16) & 1u);          // round-to-nearest-even
    return (unsigned short)(u >> 16);
}
__device__ __forceinline__ float bf2f(unsigned short s) {
    return __uint_as_float(((unsigned)s) << 16);
}
__device__ __forceinline__ float leaky(float v){ return v >= 0.f ? v : LEAKY_SLOPE * v; }

// Bijective XCD swizzle (m204): contiguous work-chunk per XCD.
__device__ __forceinline__ int xcd_swizzle(int f, int T) {
    const int q = T >> 3, r = T & 7;
    const int xcd = f & 7, i = f >> 3;
    return (xcd < r ? xcd * (q + 1) : r * (q + 1) + (xcd - r) * q) + i;
}

// ---------------------------------------------------------------------------
// Pack HWIO fp32 weights into bf16 B-fragment order for mfma_32x32x16_bf16:
// flat = (((dydx*KB + kb)*NT + nt)*64 + lane)*8 + j
// value = w[dydx][ci = kb*16 + (lane>>5)*8 + j][co = nt*32 + (lane&31)]
// ---------------------------------------------------------------------------
__global__ __launch_bounds__(256) void pack_weights(
    const float* __restrict__ src, short* __restrict__ dst,
    int CIN, int COUT, int KB, int NT, int total)
{
    int i = blockIdx.x * 256 + threadIdx.x;
    if (i >= total) return;
    int j    = i & 7;
    int lane = (i >> 3) & 63;
    int r    = i >> 9;
    int nt = r % NT; r /= NT;
    int kb = r % KB;
    int dydx = r / KB;
    int ci = kb * 16 + ((lane >> 5) << 3) + j;
    int co = nt * 32 + (lane & 31);
    float v = (ci < CIN) ? src[((size_t)dydx * CIN + ci) * COUT + co] : 0.f;
    dst[i] = (short)f2bf(v);
}

// ---------------------------------------------------------------------------
// Fused upsample + warp + cost-volume. Block = 64 px of one row.
// Output: bf16 [px][96]: ch0..63 = left, 64..68 = cost dots, 69..95 = 0.
// LDS strides are 72 shorts (144 B) for 16-B-aligned s16x8 access.
// ---------------------------------------------------------------------------
__global__ __launch_bounds__(256) void warp_costs_kernel(
    const float* __restrict__ left, const float* __restrict__ right,
    const float* __restrict__ prev, short* __restrict__ out,
    int H, int W)
{
    __shared__ float wt0s[68], wt1s[68];
    __shared__ int   i0s[68],  i1s[68];
    __shared__ __align__(16) short warp_s[68 * 72];  // [px -2..65][64ch]
    __shared__ __align__(16) short left_s[64 * 72];

    const int tid = threadIdx.x;
    const int w0 = blockIdx.x * 64;
    const int hh = blockIdx.y % H;
    const int bb = blockIdx.y / H;
    const int H2 = H >> 1, W2 = W >> 1;

    if (tid < 68) {
        int w = w0 - 2 + tid;
        float sy = 0.5f * (float)hh - 0.25f;
        float sx = 0.5f * (float)w  - 0.25f;
        float y0f = floorf(sy), x0f = floorf(sx);
        float fy = sy - y0f, fx = sx - x0f;
        int y0 = (int)y0f, x0 = (int)x0f;
        int y0c = min(max(y0, 0), H2 - 1), y1c = min(max(y0 + 1, 0), H2 - 1);
        int x0c = min(max(x0, 0), W2 - 1), x1c = min(max(x0 + 1, 0), W2 - 1);
        const float* pb = prev + (size_t)bb * H2 * W2;
        float p00 = pb[y0c * W2 + x0c], p01 = pb[y0c * W2 + x1c];
        float p10 = pb[y1c * W2 + x0c], p11 = pb[y1c * W2 + x1c];
        float disp = (1.f - fy) * ((1.f - fx) * p00 + fx * p01)
                   + fy * ((1.f - fx) * p10 + fx * p11);
        float cx = (float)w + disp;
        float xf0 = floorf(cx), xf1 = xf0 + 1.f;
        float xmax = (float)(W - 1);
        float x0s = fminf(fmaxf(xf0, 0.f), xmax);
        float x1s = fminf(fmaxf(xf1, 0.f), xmax);
        wt0s[tid] = (xf1 - cx) * (xf0 == x0s ? 1.f : 0.f);
        wt1s[tid] = (cx - xf0) * (xf1 == x1s ? 1.f : 0.f);
        i0s[tid] = (int)x0s;
        i1s[tid] = (int)x1s;
    }
    __syncthreads();

    const float* rrow = right + (size_t)(bb * H + hh) * W * 64;
    const float* lrow = left  + (size_t)(bb * H + hh) * W * 64;
    const size_t obase = ((size_t)(bb * H + hh) * W + w0) * 96;

    for (int u = tid; u < 68 * 16; u += 256) {
        int px = u >> 4, c4 = (u & 15) * 4;
        float a = wt0s[px], b = wt1s[px];
        const float4 r0 = *(const float4*)(rrow + (size_t)i0s[px] * 64 + c4);
        const float4 r1 = *(const float4*)(rrow + (size_t)i1s[px] * 64 + c4);
        s16x4 o;
        o[0] = (short)f2bf(a * r0.x + b * r1.x);
        o[1] = (short)f2bf(a * r0.y + b * r1.y);
        o[2] = (short)f2bf(a * r0.z + b * r1.z);
        o[3] = (short)f2bf(a * r0.w + b * r1.w);
        *(s16x4*)(warp_s + px * 72 + c4) = o;
    }
    for (int u = tid; u < 64 * 16; u += 256) {
        int px = u >> 4, c4 = (u & 15) * 4;
        const float4 l = *(const float4*)(lrow + ((size_t)(w0 + px)) * 64 + c4);
        s16x4 o;
        o[0] = (short)f2bf(l.x);
        o[1] = (short)f2bf(l.y);
        o[2] = (short)f2bf(l.z);
        o[3] = (short)f2bf(l.w);
        *(s16x4*)(left_s + px * 72 + c4) = o;
        *(s16x4*)(out + obase + (size_t)px * 96 + c4) = o;
    }
    // zero pad ch 69..95
    for (int u = tid; u < 64 * 3; u += 256) {
        int px = u / 3, c = 72 + (u % 3) * 8;
        s16x8 z = {0,0,0,0,0,0,0,0};
        *(s16x8*)(out + obase + (size_t)px * 96 + c) = z;
    }
    if (tid < 64) {
        out[obase + (size_t)tid * 96 + 69] = 0;
        out[obase + (size_t)tid * 96 + 70] = 0;
        out[obase + (size_t)tid * 96 + 71] = 0;
    }
    __syncthreads();

    // cost dots: 320 (px,d) tasks, vectorized s16x8 inner loop
    for (int u = tid; u < 64 * 5; u += 256) {
        int px = u / 5, d = u - px * 5;
        int x = w0 + px + d - 2;
        float s = 0.f;
        if (x >= 0 && x < W) {
            const short* lp = left_s + px * 72;
            const short* wq = warp_s + (px + d) * 72;
#pragma unroll
            for (int c8 = 0; c8 < 8; ++c8) {
                s16x8 l8 = *(const s16x8*)(lp + c8 * 8);
                s16x8 w8 = *(const s16x8*)(wq + c8 * 8);
#pragma unroll
                for (int k = 0; k < 8; ++k)
                    s += bf2f((unsigned short)l8[k]) * bf2f((unsigned short)w8[k]);
            }
        }
        out[obase + (size_t)px * 96 + 64 + d] = (short)f2bf(s * (1.f / 64.f));
    }
}

// ---------------------------------------------------------------------------
// bf16 MFMA 3x3 conv (implicit GEMM, mfma_f32_32x32x16_bf16).
// Block covers 128 px of one row x all COUT. TPB = 256 (4 waves) or 128 (2).
// Wave (wm, wn): wm owns 64 px (MT=2 m-tiles), wn owns NTW n-tiles.
// Per dy: stage row in LDS (XOR-swizzled), then 6 pipelined steps
// (3 dx x 2 half-K): B frags for step s+1 load during step s's MFMAs;
// step 0's B loads issue before the barrier (hide under barrier drain).
// Blocks XCD-swizzled (contiguous rows per XCD -> halo re-reads L2-hit).
// ---------------------------------------------------------------------------
template <int CINP, int COUT, int TPB, bool RELU>
__global__ __launch_bounds__(TPB, 3) void conv_mfma(
    const short* __restrict__ in, const short* __restrict__ wp,
    const float* __restrict__ bias, short* __restrict__ out,
    int H, int W)
{
    constexpr int KB   = CINP / 16;                  // K-steps per (dy,dx)
    constexpr int HK   = KB / 2;                     // half-K depth
    constexpr int NT   = COUT / 32;                  // n-tiles total
    constexpr int CIN8 = CINP / 8;
    constexpr int SL8  = (CINP == 96) ? 16 : CIN8;   // LDS ch8-slots/px (pow2)
    constexpr int WN   = (NT >= 2) ? 2 : 1;          // n-split ways
    constexpr int WM   = (TPB / 64) / WN;            // m-split ways
    constexpr int MT   = 4 / WM;                     // m-tiles per wave
    constexpr int NTW  = (NT + WN - 1) / WN;         // n-tiles per wave
    __shared__ __align__(16) short lds[132 * SL8 * 8];

    const int tid  = threadIdx.x;
    const int lane = tid & 63;
    const int wave = tid >> 6;
    const int wn   = wave % WN;
    const int wm   = wave / WN;
    const int l31  = lane & 31;
    const int lhi  = lane >> 5;

    // XCD-aware remap (bijective): contiguous rows per XCD, x fastest.
    const int nbx  = gridDim.x;
    const int work = xcd_swizzle(blockIdx.y * nbx + blockIdx.x,
                                 nbx * gridDim.y);
    const int w0 = (work % nbx) * 128;
    const int by = work / nbx;
    const int hh = by % H;
    const int bb = by / H;

    f32x16 acc[MT][NTW];
#pragma unroll
    for (int mt = 0; mt < MT; ++mt)
#pragma unroll
        for (int j = 0; j < NTW; ++j)
#pragma unroll
            for (int r = 0; r < 16; ++r) acc[mt][j][r] = 0.f;

    // per-lane base into packed weights: (... + lane)*8
    const short* wlane = wp + (size_t)lane * 8;
    s16x8 b[2][HK][NTW];

    for (int dy = 0; dy < 3; ++dy) {
        __syncthreads();
        const int h = hh + dy - 1;
        const bool rowok = (h >= 0) && (h < H);
        const short* src = in + (size_t)(bb * H + h) * W * CINP;
        for (int u = tid; u < 130 * CIN8; u += TPB) {
            int px = u / CIN8;
            int c8 = u - px * CIN8;
            int x = w0 - 1 + px;
            s16x8 v = {0,0,0,0,0,0,0,0};
            if (rowok && x >= 0 && x < W)
                v = *(const s16x8*)(src + (size_t)x * CINP + c8 * 8);
            *(s16x8*)(&lds[(px * SL8 + (c8 ^ (px & 7))) * 8]) = v;
        }

        // prefetch step 0 (dx=0, first half-K) BEFORE the barrier: its
        // latency hides under the staging drain + barrier.
        {
            const short* wdx0 = wlane + (size_t)((dy * 3 + 0) * KB) * NT * 512;
#pragma unroll
            for (int kk = 0; kk < HK; ++kk)
#pragma unroll
                for (int j = 0; j < NTW; ++j) {
                    const int tile = wn * NTW + j;
                    if (tile < NT)
                        b[0][kk][j] = *(const s16x8*)(
                            wdx0 + (size_t)(kk * NT + tile) * 512);
                }
        }
        __syncthreads();

        // 6 pipelined steps: step s = (dx = s>>1 ... wait, dx = s/2) no:
        // s -> dx = s>>1 is wrong for 3 dx x 2 halves; use dx = s>>1 with
        // order (dx0,h0)(dx0,h1)(dx1,h0)(dx1,h1)(dx2,h0)(dx2,h1).
#pragma unroll
        for (int s = 0; s < 6; ++s) {
            // issue B loads for step s+1 into the other buffer
            if (s < 5) {
                const int sn  = s + 1;
                const int dxn = sn >> 1, hn = sn & 1;
                const short* wdxn = wlane + (size_t)((dy * 3 + dxn) * KB) * NT * 512;
#pragma unroll
                for (int kk = 0; kk < HK; ++kk)
#pragma unroll
                    for (int j = 0; j < NTW; ++j) {
                        const int tile = wn * NTW + j;
                        if (tile < NT)
                            b[sn & 1][kk][j] = *(const s16x8*)(
                                wdxn + (size_t)((hn * HK + kk) * NT + tile) * 512);
                    }
            }
            // MFMA half-K of step s
            const int dx = s >> 1, h0k = (s & 1) * HK;
#pragma unroll
            for (int kk = 0; kk < HK; ++kk) {
                const int kb  = h0k + kk;
                const int c8r = kb * 2 + lhi;
                s16x8 a[MT];
#pragma unroll
                for (int mt = 0; mt < MT; ++mt) {
                    const int px = (wm * MT + mt) * 32 + l31 + dx;
                    a[mt] = *(const s16x8*)(&lds[(px * SL8 + (c8r ^ (px & 7))) * 8]);
                }
#pragma unroll
                for (int j = 0; j < NTW; ++j) {
                    if (wn * NTW + j >= NT) continue;
#pragma unroll
                    for (int mt = 0; mt < MT; ++mt)
                        acc[mt][j] = __builtin_amdgcn_mfma_f32_32x32x16_bf16(
                            a[mt], b[s & 1][kk][j], acc[mt][j], 0, 0, 0);
                }
            }
        }
    }

    // epilogue: C/D layout col(co)=lane&31, row(px)=(r&3)+8*(r>>2)+4*(lane>>5)
    const size_t rowbase = (size_t)(bb * H + hh) * W + w0;
#pragma unroll
    for (int j = 0; j < NTW; ++j) {
        const int tile = wn * NTW + j;
        if (tile >= NT) continue;
        const int co = tile * 32 + l31;
        const float bv = bias[co];
#pragma unroll
        for (int mt = 0; mt < MT; ++mt) {
            const int pxb = (wm * MT + mt) * 32 + 4 * lhi;
#pragma unroll
            for (int r = 0; r < 16; ++r) {
                int px = pxb + (r & 3) + 8 * (r >> 2);
                float v = acc[mt][j][r] + bv;
                if (RELU) v = leaky(v);
                out[(rowbase + px) * COUT + co] = (short)f2bf(v);
            }
        }
    }
}

// ---------------------------------------------------------------------------
// Final conv 32 -> 1, linear, bf16 in / fp32 out. One thread per pixel.
// XCD-swizzled block index for dy-halo L2 locality.
// ---------------------------------------------------------------------------
__global__ __launch_bounds__(256) void conv_last_kernel(
    const short* __restrict__ in, const float* __restrict__ wgt,
    const float* __restrict__ bias, float* __restrict__ out,
    int H, int W, int npx)
{
    int blk = xcd_swizzle(blockIdx.x, gridDim.x);
    int idx = blk * 256 + threadIdx.x;
    if (idx >= npx) return;
    int w = idx % W;
    int t = idx / W;
    int h = t % H;
    int b = t / H;

    float acc = bias[0];
#pragma unroll
    for (int dy = 0; dy < 3; ++dy) {
        int hy = h + dy - 1;
        if (hy < 0 || hy >= H) continue;
#pragma unroll
        for (int dx = 0; dx < 3; ++dx) {
            int x = w + dx - 1;
            if (x < 0 || x >= W) continue;
            const short* p = in + ((size_t)(b * H + hy) * W + x) * 32;
            const float* wk = wgt + (dy * 3 + dx) * 32;
#pragma unroll
            for (int c8 = 0; c8 < 4; ++c8) {
                s16x8 v = *(const s16x8*)(p + c8 * 8);
#pragma unroll
                for (int k = 0; k < 8; ++k)
                    acc += bf2f((unsigned short)v[k]) * wk[c8 * 8 + k];
            }
        }
    }
    out[idx] = acc;
}

// ---------------------------------------------------------------------------
extern "C" void kernel_launch(void* const* d_in, const int* in_sizes, int n_in,
                              void* d_out, int out_size, void* d_ws, size_t ws_size,
                              hipStream_t stream)
{
    constexpr int B = 4, H = 192, W = 640;
    constexpr int HW = H * W;          // 122880

    const float* left  = (const float*)d_in[0];
    const float* right = (const float*)d_in[1];
    const float* prev  = (const float*)d_in[2];
    const float* w1 = (const float*)d_in[4];
    const float* b1 = (const float*)d_in[5];
    const float* w2 = (const float*)d_in[6];
    const float* b2 = (const float*)d_in[7];
    const float* w3 = (const float*)d_in[8];
    const float* b3 = (const float*)d_in[9];
    const float* w4 = (const float*)d_in[10];
    const float* b4 = (const float*)d_in[11];
    const float* w5 = (const float*)d_in[12];
    const float* b5 = (const float*)d_in[13];
    const float* w6 = (const float*)d_in[14];
    const float* b6 = (const float*)d_in[15];
    float* out = (float*)d_out;

    // Packed-weight region (shorts), then bf16 activation ping-pong X/Y.
    constexpr int S1 = 9 * 6 * 4 * 512;   // conv1: CINP 96,  COUT 128
    constexpr int S2 = 9 * 8 * 4 * 512;   // conv2: 128 -> 128
    constexpr int S3 = 9 * 8 * 3 * 512;   // conv3: 128 -> 96
    constexpr int S4 = 9 * 6 * 2 * 512;   // conv4: 96  -> 64
    constexpr int S5 = 9 * 4 * 1 * 512;   // conv5: 64  -> 32
    constexpr int P1 = 0, P2 = P1 + S1, P3 = P2 + S2, P4 = P3 + S3, P5 = P4 + S4;
    constexpr size_t WPAD = 524288;       // 1 MiB reserved (in shorts)

    short* wsS = (short*)d_ws;
    pack_weights<<<(S1 + 255) / 256, 256, 0, stream>>>(w1, wsS + P1,  69, 128, 6, 4, S1);
    pack_weights<<<(S2 + 255) / 256, 256, 0, stream>>>(w2, wsS + P2, 128, 128, 8, 4, S2);
    pack_weights<<<(S3 + 255) / 256, 256, 0, stream>>>(w3, wsS + P3, 128,  96, 8, 3, S3);
    pack_weights<<<(S4 + 255) / 256, 256, 0, stream>>>(w4, wsS + P4,  96,  64, 6, 2, S4);
    pack_weights<<<(S5 + 255) / 256, 256, 0, stream>>>(w5, wsS + P5,  64,  32, 4, 1, S5);

    // batch tiling from ws_size (deterministic -> graph-capture safe)
    auto need = [&](int nb) -> size_t {
        return (WPAD + 2ull * nb * HW * 128) * sizeof(short);
    };
    int nb = 1;
    if (ws_size >= need(4)) nb = 4;
    else if (ws_size >= need(2)) nb = 2;

    const int H2 = H / 2, W2 = W / 2;

    for (int b0 = 0; b0 < B; b0 += nb) {
        const int npx = nb * HW;
        short* X = wsS + WPAD;
        short* Y = X + (size_t)nb * HW * 128;

        const float* leftb  = left  + (size_t)b0 * HW * 64;
        const float* rightb = right + (size_t)b0 * HW * 64;
        const float* prevb  = prev  + (size_t)b0 * H2 * W2;
        float* outb = out + (size_t)b0 * HW;

        warp_costs_kernel<<<dim3(W / 64, nb * H), 256, 0, stream>>>(
            leftb, rightb, prevb, X, H, W);

        conv_mfma< 96, 128, 256, true><<<dim3(W / 128, nb * H), 256, 0, stream>>>(
            X, wsS + P1, b1, Y, H, W);
        conv_mfma<128, 128, 256, true><<<dim3(W / 128, nb * H), 256, 0, stream>>>(
            Y, wsS + P2, b2, X, H, W);
        conv_mfma<128,  96, 256, true><<<dim3(W / 128, nb * H), 256, 0, stream>>>(
            X, wsS + P3, b3, Y, H, W);
        conv_mfma< 96,  64, 256, true><<<dim3(W / 128, nb * H), 256, 0, stream>>>(
            Y, wsS + P4, b4, X, H, W);
        conv_mfma< 64,  32, 128, true><<<dim3(W / 128, nb * H), 128, 0, stream>>>(
            X, wsS + P5, b5, Y, H, W);

        conv_last_kernel<<<(npx + 255) / 256, 256, 0, stream>>>(
            Y, w6, b6, outb, H, W, npx);
    }
}

// Round 3
// 913.020 us; speedup vs baseline: 1.0564x; 1.0520x over previous
//
#include <hip/hip_runtime.h>
#include <cstdint>
#include <cstddef>

// Problem dims: B=4, H=192, W=640, C=64, sr=2
// Conv chans: 69 -> 128 -> 128 -> 96 -> 64 -> 32 -> 1, 3x3 SAME, NHWC/HWIO.
//
// Round 6 -> 7: B-fragment reg double-buffer — FAILED (neutral): VGPR=84
// proves compiler sank the prefetch back to just-before-use. Source-level
// pipelining through register destinations is defeatable.
// Round 7 -> 8: compiler-proof pipeline.
//  (1) A-row staging via __builtin_amdgcn_global_load_lds into a 2-deep
//      LDS ring: DMA for row dy+1 issues right after the dy barrier and
//      completes under dy's compute; __syncthreads' vmcnt(0) drain is then
//      free. DMA has no reg result -> cannot be sunk. XOR bank-swizzle is
//      folded into the per-lane GLOBAL source address (LDS dest linear);
//      OOB/phantom lanes redirect source to a 128B zero region in ws.
//  (2) B weights prefetched one full (dy,dx) chunk ahead (9 static steps,
//      named bA/bB, literal indices), __launch_bounds__(TPB,2) for the
//      ~230-reg budget. LDS 74KB -> 2 blocks/CU, but blocks only stall on
//      3 barriers total.

#define LEAKY_SLOPE 0.2f

typedef float  f32x16 __attribute__((ext_vector_type(16)));
typedef short  s16x8  __attribute__((ext_vector_type(8)));
typedef short  s16x4  __attribute__((ext_vector_type(4)));

__device__ __forceinline__ unsigned short f2bf(float f) {
    unsigned u = __float_as_uint(f);
    u += 0x7FFFu + ((u >> 16) & 1u);          // round-to-nearest-even
    return (unsigned short)(u >> 16);
}
__device__ __forceinline__ float bf2f(unsigned short s) {
    return __uint_as_float(((unsigned)s) << 16);
}
__device__ __forceinline__ float leaky(float v){ return v >= 0.f ? v : LEAKY_SLOPE * v; }

// async 16B global->LDS DMA (gfx950). LDS dest = wave-uniform base + lane*16.
__device__ __forceinline__ void async16(const void* g, void* l) {
    __builtin_amdgcn_global_load_lds(
        (__attribute__((address_space(1))) void*)g,
        (__attribute__((address_space(3))) void*)l, 16, 0, 0);
}

// Bijective XCD swizzle (m204): contiguous work-chunk per XCD.
__device__ __forceinline__ int xcd_swizzle(int f, int T) {
    const int q = T >> 3, r = T & 7;
    const int xcd = f & 7, i = f >> 3;
    return (xcd < r ? xcd * (q + 1) : r * (q + 1) + (xcd - r) * q) + i;
}

// ---------------------------------------------------------------------------
// Pack HWIO fp32 weights into bf16 B-fragment order for mfma_32x32x16_bf16:
// flat = (((dydx*KB + kb)*NT + nt)*64 + lane)*8 + j
// value = w[dydx][ci = kb*16 + (lane>>5)*8 + j][co = nt*32 + (lane&31)]
// ---------------------------------------------------------------------------
__global__ __launch_bounds__(256) void pack_weights(
    const float* __restrict__ src, short* __restrict__ dst,
    int CIN, int COUT, int KB, int NT, int total)
{
    int i = blockIdx.x * 256 + threadIdx.x;
    if (i >= total) return;
    int j    = i & 7;
    int lane = (i >> 3) & 63;
    int r    = i >> 9;
    int nt = r % NT; r /= NT;
    int kb = r % KB;
    int dydx = r / KB;
    int ci = kb * 16 + ((lane >> 5) << 3) + j;
    int co = nt * 32 + (lane & 31);
    float v = (ci < CIN) ? src[((size_t)dydx * CIN + ci) * COUT + co] : 0.f;
    dst[i] = (short)f2bf(v);
}

__global__ __launch_bounds__(64) void zero_fill(short* p) {
    p[threadIdx.x] = 0;
}

// ---------------------------------------------------------------------------
// Fused upsample + warp + cost-volume. Block = 64 px of one row.
// Output: bf16 [px][96]: ch0..63 = left, 64..68 = cost dots, 69..95 = 0.
// ---------------------------------------------------------------------------
__global__ __launch_bounds__(256) void warp_costs_kernel(
    const float* __restrict__ left, const float* __restrict__ right,
    const float* __restrict__ prev, short* __restrict__ out,
    int H, int W)
{
    __shared__ float wt0s[68], wt1s[68];
    __shared__ int   i0s[68],  i1s[68];
    __shared__ __align__(16) short warp_s[68 * 72];  // [px -2..65][64ch]
    __shared__ __align__(16) short left_s[64 * 72];

    const int tid = threadIdx.x;
    const int w0 = blockIdx.x * 64;
    const int hh = blockIdx.y % H;
    const int bb = blockIdx.y / H;
    const int H2 = H >> 1, W2 = W >> 1;

    if (tid < 68) {
        int w = w0 - 2 + tid;
        float sy = 0.5f * (float)hh - 0.25f;
        float sx = 0.5f * (float)w  - 0.25f;
        float y0f = floorf(sy), x0f = floorf(sx);
        float fy = sy - y0f, fx = sx - x0f;
        int y0 = (int)y0f, x0 = (int)x0f;
        int y0c = min(max(y0, 0), H2 - 1), y1c = min(max(y0 + 1, 0), H2 - 1);
        int x0c = min(max(x0, 0), W2 - 1), x1c = min(max(x0 + 1, 0), W2 - 1);
        const float* pb = prev + (size_t)bb * H2 * W2;
        float p00 = pb[y0c * W2 + x0c], p01 = pb[y0c * W2 + x1c];
        float p10 = pb[y1c * W2 + x0c], p11 = pb[y1c * W2 + x1c];
        float disp = (1.f - fy) * ((1.f - fx) * p00 + fx * p01)
                   + fy * ((1.f - fx) * p10 + fx * p11);
        float cx = (float)w + disp;
        float xf0 = floorf(cx), xf1 = xf0 + 1.f;
        float xmax = (float)(W - 1);
        float x0s = fminf(fmaxf(xf0, 0.f), xmax);
        float x1s = fminf(fmaxf(xf1, 0.f), xmax);
        wt0s[tid] = (xf1 - cx) * (xf0 == x0s ? 1.f : 0.f);
        wt1s[tid] = (cx - xf0) * (xf1 == x1s ? 1.f : 0.f);
        i0s[tid] = (int)x0s;
        i1s[tid] = (int)x1s;
    }
    __syncthreads();

    const float* rrow = right + (size_t)(bb * H + hh) * W * 64;
    const float* lrow = left  + (size_t)(bb * H + hh) * W * 64;
    const size_t obase = ((size_t)(bb * H + hh) * W + w0) * 96;

    for (int u = tid; u < 68 * 16; u += 256) {
        int px = u >> 4, c4 = (u & 15) * 4;
        float a = wt0s[px], b = wt1s[px];
        const float4 r0 = *(const float4*)(rrow + (size_t)i0s[px] * 64 + c4);
        const float4 r1 = *(const float4*)(rrow + (size_t)i1s[px] * 64 + c4);
        s16x4 o;
        o[0] = (short)f2bf(a * r0.x + b * r1.x);
        o[1] = (short)f2bf(a * r0.y + b * r1.y);
        o[2] = (short)f2bf(a * r0.z + b * r1.z);
        o[3] = (short)f2bf(a * r0.w + b * r1.w);
        *(s16x4*)(warp_s + px * 72 + c4) = o;
    }
    for (int u = tid; u < 64 * 16; u += 256) {
        int px = u >> 4, c4 = (u & 15) * 4;
        const float4 l = *(const float4*)(lrow + ((size_t)(w0 + px)) * 64 + c4);
        s16x4 o;
        o[0] = (short)f2bf(l.x);
        o[1] = (short)f2bf(l.y);
        o[2] = (short)f2bf(l.z);
        o[3] = (short)f2bf(l.w);
        *(s16x4*)(left_s + px * 72 + c4) = o;
        *(s16x4*)(out + obase + (size_t)px * 96 + c4) = o;
    }
    // zero pad ch 69..95
    for (int u = tid; u < 64 * 3; u += 256) {
        int px = u / 3, c = 72 + (u % 3) * 8;
        s16x8 z = {0,0,0,0,0,0,0,0};
        *(s16x8*)(out + obase + (size_t)px * 96 + c) = z;
    }
    if (tid < 64) {
        out[obase + (size_t)tid * 96 + 69] = 0;
        out[obase + (size_t)tid * 96 + 70] = 0;
        out[obase + (size_t)tid * 96 + 71] = 0;
    }
    __syncthreads();

    // cost dots: 320 (px,d) tasks, vectorized s16x8 inner loop
    for (int u = tid; u < 64 * 5; u += 256) {
        int px = u / 5, d = u - px * 5;
        int x = w0 + px + d - 2;
        float s = 0.f;
        if (x >= 0 && x < W) {
            const short* lp = left_s + px * 72;
            const short* wq = warp_s + (px + d) * 72;
#pragma unroll
            for (int c8 = 0; c8 < 8; ++c8) {
                s16x8 l8 = *(const s16x8*)(lp + c8 * 8);
                s16x8 w8 = *(const s16x8*)(wq + c8 * 8);
#pragma unroll
                for (int k = 0; k < 8; ++k)
                    s += bf2f((unsigned short)l8[k]) * bf2f((unsigned short)w8[k]);
            }
        }
        out[obase + (size_t)px * 96 + 64 + d] = (short)f2bf(s * (1.f / 64.f));
    }
}

// ---------------------------------------------------------------------------
// bf16 MFMA 3x3 conv (implicit GEMM, mfma_f32_32x32x16_bf16).
// Block = 128 px of one row x all COUT. Waves split WM x WN.
// A rows: 2-deep LDS ring filled by global_load_lds DMA (issued one dy
// ahead, drained for free by the next __syncthreads). XOR swizzle folded
// into per-lane global source address; LDS linear in (px,slot).
// B weights: one full (dy,dx) chunk prefetched ahead in named regs.
// ---------------------------------------------------------------------------
template <int CINP, int COUT, int TPB, bool RELU>
__global__ __launch_bounds__(TPB, 2) void conv_mfma(
    const short* __restrict__ in, const short* __restrict__ wp,
    const float* __restrict__ bias, short* __restrict__ out,
    const short* __restrict__ zerobuf, int H, int W)
{
    constexpr int KB   = CINP / 16;                  // K-steps per (dy,dx)
    constexpr int NT   = COUT / 32;                  // n-tiles total
    constexpr int CIN8 = CINP / 8;
    constexpr int SL8  = (CINP == 96) ? 16 : CIN8;   // LDS ch8-slots/px (pow2)
    constexpr int SH   = (SL8 == 16) ? 4 : 3;        // log2(SL8)
    constexpr int WN   = (NT >= 2) ? 2 : 1;          // n-split ways
    constexpr int WM   = (TPB / 64) / WN;            // m-split ways
    constexpr int MT   = 4 / WM;                     // m-tiles per wave
    constexpr int NTW  = (NT + WN - 1) / WN;         // n-tiles per wave
    constexpr int TASKS = 130 * SL8;                 // real 16B stage tasks
    constexpr int NITER = (TASKS + TPB - 1) / TPB;   // DMA iters (uniform)
    constexpr int BUFSHORTS = NITER * TPB * 8;       // padded buffer size
    __shared__ __align__(16) short lds[2 * BUFSHORTS];

    const int tid  = threadIdx.x;
    const int lane = tid & 63;
    const int wave = tid >> 6;
    const int wn   = wave % WN;
    const int wm   = wave / WN;
    const int l31  = lane & 31;
    const int lhi  = lane >> 5;

    // XCD-aware remap (bijective): contiguous rows per XCD, x fastest.
    const int nbx  = gridDim.x;
    const int work = xcd_swizzle(blockIdx.y * nbx + blockIdx.x,
                                 nbx * gridDim.y);
    const int w0 = (work % nbx) * 128;
    const int by = work / nbx;
    const int hh = by % H;
    const int bb = by / H;

    // issue DMA stage of input row H_ into ring buffer SEL (0/1).
    // per-lane source carries the XOR swizzle + all boundary/phantom
    // redirection (to zerobuf); LDS dest is linear: task u -> lds[u*8].
#define ISSUE_STAGE(SEL, H_) do {                                          \
        const int h_ = (H_);                                               \
        const bool rowok_ = (h_ >= 0) && (h_ < H);                         \
        const short* src_ = in + (size_t)(bb * H + (rowok_ ? h_ : 0)) * W * CINP; \
        short* lb_ = lds + (SEL) * BUFSHORTS;                              \
        _Pragma("unroll")                                                  \
        for (int k_ = 0; k_ < NITER; ++k_) {                               \
            const int u_  = tid + k_ * TPB;                                \
            const int px_ = u_ >> SH;                                      \
            const int s_  = u_ & (SL8 - 1);                                \
            const int sc_ = s_ ^ (px_ & 7);                                \
            const int x_  = w0 - 1 + px_;                                  \
            const bool ok_ = rowok_ && (x_ >= 0) && (x_ < W) &&            \
                             (sc_ < CIN8) && (u_ < TASKS);                 \
            const short* g_ = ok_ ? (src_ + (size_t)x_ * CINP + sc_ * 8)   \
                                  : zerobuf;                               \
            async16(g_, lb_ + (size_t)(u_ - lane) * 8);                    \
        }                                                                  \
    } while (0)

    // load B chunk (DY,DX) into named buffer BUF (literal indices only).
#define LOADB(BUF, DY, DX) do {                                            \
        const short* wdx_ = wlane + (size_t)(((DY) * 3 + (DX)) * KB) * NT * 512; \
        _Pragma("unroll")                                                  \
        for (int kb_ = 0; kb_ < KB; ++kb_)                                 \
        _Pragma("unroll")                                                  \
        for (int j_ = 0; j_ < NTW; ++j_) {                                 \
            const int tile_ = wn * NTW + j_;                               \
            if (tile_ < NT)                                                \
                BUF[kb_][j_] = *(const s16x8*)(wdx_ + (size_t)(kb_ * NT + tile_) * 512); \
        }                                                                  \
    } while (0)

    // run KB k-steps of one dx using B buffer BUF against abuf rows.
#define MFMA_STEP(BUF, DX) do {                                            \
        _Pragma("unroll")                                                  \
        for (int kb_ = 0; kb_ < KB; ++kb_) {                               \
            const int c8r_ = kb_ * 2 + lhi;                                \
            s16x8 a_[MT];                                                  \
            _Pragma("unroll")                                              \
            for (int mt_ = 0; mt_ < MT; ++mt_) {                           \
                const int px_ = (wm * MT + mt_) * 32 + l31 + (DX);         \
                a_[mt_] = *(const s16x8*)(&abuf[(px_ * SL8 + (c8r_ ^ (px_ & 7))) * 8]); \
            }                                                              \
            _Pragma("unroll")                                              \
            for (int j_ = 0; j_ < NTW; ++j_) {                             \
                if (wn * NTW + j_ >= NT) continue;                         \
                _Pragma("unroll")                                          \
                for (int mt_ = 0; mt_ < MT; ++mt_)                         \
                    acc[mt_][j_] = __builtin_amdgcn_mfma_f32_32x32x16_bf16( \
                        a_[mt_], BUF[kb_][j_], acc[mt_][j_], 0, 0, 0);     \
            }                                                              \
        }                                                                  \
    } while (0)

    f32x16 acc[MT][NTW];
#pragma unroll
    for (int mt = 0; mt < MT; ++mt)
#pragma unroll
        for (int j = 0; j < NTW; ++j)
#pragma unroll
            for (int r = 0; r < 16; ++r) acc[mt][j][r] = 0.f;

    const short* wlane = wp + (size_t)lane * 8;
    s16x8 bA[KB][NTW], bB[KB][NTW];

    // prologue: stage row dy=0 (hh-1) into buf0; prefetch B chunk 0.
    ISSUE_STAGE(0, hh - 1);
    LOADB(bA, 0, 0);

#pragma unroll
    for (int dy = 0; dy < 3; ++dy) {
        // __syncthreads drains vmcnt(0) (stage DMA done, ~free) + barrier:
        // publishes buf[dy&1]; all waves past previous compute -> safe to
        // overwrite buf[(dy+1)&1] after this point.
        __syncthreads();
        if (dy < 2) ISSUE_STAGE((dy + 1) & 1, hh + dy);
        const short* abuf = lds + (dy & 1) * BUFSHORTS;
#pragma unroll
        for (int dx = 0; dx < 3; ++dx) {
            const int c = dy * 3 + dx;     // chunk index 0..8, literal
            if ((c & 1) == 0) {
                if (c < 8) LOADB(bB, (c + 1) / 3, (c + 1) % 3);
                MFMA_STEP(bA, dx);
            } else {
                if (c < 8) LOADB(bA, (c + 1) / 3, (c + 1) % 3);
                MFMA_STEP(bB, dx);
            }
        }
    }
#undef ISSUE_STAGE
#undef LOADB
#undef MFMA_STEP

    // epilogue: C/D layout col(co)=lane&31, row(px)=(r&3)+8*(r>>2)+4*(lane>>5)
    const size_t rowbase = (size_t)(bb * H + hh) * W + w0;
#pragma unroll
    for (int j = 0; j < NTW; ++j) {
        const int tile = wn * NTW + j;
        if (tile >= NT) continue;
        const int co = tile * 32 + l31;
        const float bv = bias[co];
#pragma unroll
        for (int mt = 0; mt < MT; ++mt) {
            const int pxb = (wm * MT + mt) * 32 + 4 * lhi;
#pragma unroll
            for (int r = 0; r < 16; ++r) {
                int px = pxb + (r & 3) + 8 * (r >> 2);
                float v = acc[mt][j][r] + bv;
                if (RELU) v = leaky(v);
                out[(rowbase + px) * COUT + co] = (short)f2bf(v);
            }
        }
    }
}

// ---------------------------------------------------------------------------
// Final conv 32 -> 1, linear, bf16 in / fp32 out. One thread per pixel.
// XCD-swizzled block index for dy-halo L2 locality.
// ---------------------------------------------------------------------------
__global__ __launch_bounds__(256) void conv_last_kernel(
    const short* __restrict__ in, const float* __restrict__ wgt,
    const float* __restrict__ bias, float* __restrict__ out,
    int H, int W, int npx)
{
    int blk = xcd_swizzle(blockIdx.x, gridDim.x);
    int idx = blk * 256 + threadIdx.x;
    if (idx >= npx) return;
    int w = idx % W;
    int t = idx / W;
    int h = t % H;
    int b = t / H;

    float acc = bias[0];
#pragma unroll
    for (int dy = 0; dy < 3; ++dy) {
        int hy = h + dy - 1;
        if (hy < 0 || hy >= H) continue;
#pragma unroll
        for (int dx = 0; dx < 3; ++dx) {
            int x = w + dx - 1;
            if (x < 0 || x >= W) continue;
            const short* p = in + ((size_t)(b * H + hy) * W + x) * 32;
            const float* wk = wgt + (dy * 3 + dx) * 32;
#pragma unroll
            for (int c8 = 0; c8 < 4; ++c8) {
                s16x8 v = *(const s16x8*)(p + c8 * 8);
#pragma unroll
                for (int k = 0; k < 8; ++k)
                    acc += bf2f((unsigned short)v[k]) * wk[c8 * 8 + k];
            }
        }
    }
    out[idx] = acc;
}

// ---------------------------------------------------------------------------
extern "C" void kernel_launch(void* const* d_in, const int* in_sizes, int n_in,
                              void* d_out, int out_size, void* d_ws, size_t ws_size,
                              hipStream_t stream)
{
    constexpr int B = 4, H = 192, W = 640;
    constexpr int HW = H * W;          // 122880

    const float* left  = (const float*)d_in[0];
    const float* right = (const float*)d_in[1];
    const float* prev  = (const float*)d_in[2];
    const float* w1 = (const float*)d_in[4];
    const float* b1 = (const float*)d_in[5];
    const float* w2 = (const float*)d_in[6];
    const float* b2 = (const float*)d_in[7];
    const float* w3 = (const float*)d_in[8];
    const float* b3 = (const float*)d_in[9];
    const float* w4 = (const float*)d_in[10];
    const float* b4 = (const float*)d_in[11];
    const float* w5 = (const float*)d_in[12];
    const float* b5 = (const float*)d_in[13];
    const float* w6 = (const float*)d_in[14];
    const float* b6 = (const float*)d_in[15];
    float* out = (float*)d_out;

    // Packed-weight region (shorts), then bf16 activation ping-pong X/Y.
    constexpr int S1 = 9 * 6 * 4 * 512;   // conv1: CINP 96,  COUT 128
    constexpr int S2 = 9 * 8 * 4 * 512;   // conv2: 128 -> 128
    constexpr int S3 = 9 * 8 * 3 * 512;   // conv3: 128 -> 96
    constexpr int S4 = 9 * 6 * 2 * 512;   // conv4: 96  -> 64
    constexpr int S5 = 9 * 4 * 1 * 512;   // conv5: 64  -> 32
    constexpr int P1 = 0, P2 = P1 + S1, P3 = P2 + S2, P4 = P3 + S3, P5 = P4 + S4;
    constexpr size_t WPAD = 524288;       // 1 MiB reserved (in shorts)
    constexpr size_t ZOFF = WPAD - 64;    // 128B zero region for DMA redirect

    short* wsS = (short*)d_ws;
    pack_weights<<<(S1 + 255) / 256, 256, 0, stream>>>(w1, wsS + P1,  69, 128, 6, 4, S1);
    pack_weights<<<(S2 + 255) / 256, 256, 0, stream>>>(w2, wsS + P2, 128, 128, 8, 4, S2);
    pack_weights<<<(S3 + 255) / 256, 256, 0, stream>>>(w3, wsS + P3, 128,  96, 8, 3, S3);
    pack_weights<<<(S4 + 255) / 256, 256, 0, stream>>>(w4, wsS + P4,  96,  64, 6, 2, S4);
    pack_weights<<<(S5 + 255) / 256, 256, 0, stream>>>(w5, wsS + P5,  64,  32, 4, 1, S5);
    zero_fill<<<1, 64, 0, stream>>>(wsS + ZOFF);
    const short* zb = wsS + ZOFF;

    // batch tiling from ws_size (deterministic -> graph-capture safe)
    auto need = [&](int nb) -> size_t {
        return (WPAD + 2ull * nb * HW * 128) * sizeof(short);
    };
    int nb = 1;
    if (ws_size >= need(4)) nb = 4;
    else if (ws_size >= need(2)) nb = 2;

    const int H2 = H / 2, W2 = W / 2;

    for (int b0 = 0; b0 < B; b0 += nb) {
        const int npx = nb * HW;
        short* X = wsS + WPAD;
        short* Y = X + (size_t)nb * HW * 128;

        const float* leftb  = left  + (size_t)b0 * HW * 64;
        const float* rightb = right + (size_t)b0 * HW * 64;
        const float* prevb  = prev  + (size_t)b0 * H2 * W2;
        float* outb = out + (size_t)b0 * HW;

        warp_costs_kernel<<<dim3(W / 64, nb * H), 256, 0, stream>>>(
            leftb, rightb, prevb, X, H, W);

        conv_mfma< 96, 128, 256, true><<<dim3(W / 128, nb * H), 256, 0, stream>>>(
            X, wsS + P1, b1, Y, zb, H, W);
        conv_mfma<128, 128, 256, true><<<dim3(W / 128, nb * H), 256, 0, stream>>>(
            Y, wsS + P2, b2, X, zb, H, W);
        conv_mfma<128,  96, 256, true><<<dim3(W / 128, nb * H), 256, 0, stream>>>(
            X, wsS + P3, b3, Y, zb, H, W);
        conv_mfma< 96,  64, 256, true><<<dim3(W / 128, nb * H), 256, 0, stream>>>(
            Y, wsS + P4, b4, X, zb, H, W);
        conv_mfma< 64,  32, 128, true><<<dim3(W / 128, nb * H), 128, 0, stream>>>(
            X, wsS + P5, b5, Y, zb, H, W);

        conv_last_kernel<<<(npx + 255) / 256, 256, 0, stream>>>(
            Y, w6, b6, outb, H, W, npx);
    }
}